// Round 1
// baseline (804.420 us; speedup 1.0000x reference)
//
#include <hip/hip_runtime.h>
#include <hip/hip_bf16.h>

// Problem constants
#define NN 4096
#define DD 1024
#define HH 16
#define HDD 64
#define NO 24
#define QKV_N (3 * DD)

__device__ __constant__ int OFFSETS[NO] = {0, 1, 2, 3, 4, 6, 8, 12, 16, 24, 32, 48,
                                           64, 96, 128, 192, 256, 384, 512, 768,
                                           1024, 1536, 2048, 3072};

// ---------------------------------------------------------------------------
// Generic fp32 tiled GEMM: C[M,N] = A[M,K] @ B[K,N] + bias[N], optional epilogue.
// OP==0: C = acc + bias
// OP==1: C = mult[m,n] * sigmoid(acc + bias)
// 64x64 tile, BK=16, 256 threads, 4x4 micro-tile per thread.
// M % 64 == 0, N % 64 == 0, K % 16 == 0 (all true here).
// ---------------------------------------------------------------------------
template <int OP>
__global__ __launch_bounds__(256) void sgemm64(const float* __restrict__ A,
                                               const float* __restrict__ Bm,
                                               const float* __restrict__ bias,
                                               const float* __restrict__ mult,
                                               float* __restrict__ C,
                                               int M, int N, int K) {
    __shared__ float As[16][68];  // transposed A tile: As[k][m], padded
    __shared__ float Bs[16][68];  // Bs[k][n], padded (68*4 bytes keeps 16B align)

    const int tid = threadIdx.x;
    const int tx = tid & 15;   // output col group
    const int ty = tid >> 4;   // output row group
    const int n0 = blockIdx.x * 64;
    const int m0 = blockIdx.y * 64;

    // A-load coords: row r (0..63), 4 cols starting at ca
    const int ar = tid >> 2;
    const int ac = (tid & 3) * 4;
    // B-load coords: row rk (0..15), 4 cols starting at cn
    const int brk = tid >> 4;
    const int bcn = (tid & 15) * 4;

    float acc[4][4];
#pragma unroll
    for (int i = 0; i < 4; ++i)
#pragma unroll
        for (int j = 0; j < 4; ++j) acc[i][j] = 0.f;

    for (int k0 = 0; k0 < K; k0 += 16) {
        float4 av = *(const float4*)&A[(size_t)(m0 + ar) * K + k0 + ac];
        As[ac + 0][ar] = av.x;
        As[ac + 1][ar] = av.y;
        As[ac + 2][ar] = av.z;
        As[ac + 3][ar] = av.w;
        *(float4*)&Bs[brk][bcn] =
            *(const float4*)&Bm[(size_t)(k0 + brk) * N + n0 + bcn];
        __syncthreads();

#pragma unroll
        for (int kk = 0; kk < 16; ++kk) {
            float4 a = *(const float4*)&As[kk][ty * 4];
            float4 b = *(const float4*)&Bs[kk][tx * 4];
            float av4[4] = {a.x, a.y, a.z, a.w};
            float bv4[4] = {b.x, b.y, b.z, b.w};
#pragma unroll
            for (int i = 0; i < 4; ++i)
#pragma unroll
                for (int j = 0; j < 4; ++j) acc[i][j] = fmaf(av4[i], bv4[j], acc[i][j]);
        }
        __syncthreads();
    }

#pragma unroll
    for (int i = 0; i < 4; ++i) {
        const int m = m0 + ty * 4 + i;
#pragma unroll
        for (int j = 0; j < 4; ++j) {
            const int n = n0 + tx * 4 + j;
            float v = acc[i][j] + bias[n];
            if (OP == 1) {
                v = mult[(size_t)m * N + n] / (1.f + expf(-v));
            }
            C[(size_t)m * N + n] = v;
        }
    }
}

// ---------------------------------------------------------------------------
// Attention: one wave per (t, h). lane = head dim d (0..63).
// scores over 24 taps; invalid taps (t < delta) keep score = pos_bias (they
// stay in the softmax denominator) but contribute zero value.
// qkv: [N, 3D] with q cols [0,1024), k cols [1024,2048), v cols [2048,3072).
// ---------------------------------------------------------------------------
__global__ __launch_bounds__(256) void attn_kernel(const float* __restrict__ qkv,
                                                   const float* __restrict__ pos_bias,
                                                   float* __restrict__ outf) {
    const int gwave = (blockIdx.x * 256 + threadIdx.x) >> 6;
    const int lane = threadIdx.x & 63;
    const int t = gwave >> 4;
    const int h = gwave & 15;
    const float scale = 0.125f;  // 64^-0.5

    const float q = qkv[(size_t)t * QKV_N + h * HDD + lane];

    float scores[NO];
#pragma unroll
    for (int j = 0; j < NO; ++j) {
        const int dlt = OFFSETS[j];
        float s = pos_bias[j * HH + h];
        if (t >= dlt) {  // wave-uniform branch
            float p = q * qkv[(size_t)(t - dlt) * QKV_N + DD + h * HDD + lane];
#pragma unroll
            for (int off = 32; off; off >>= 1) p += __shfl_xor(p, off);
            s = fmaf(p, scale, s);
        }
        scores[j] = s;
    }

    float mx = scores[0];
#pragma unroll
    for (int j = 1; j < NO; ++j) mx = fmaxf(mx, scores[j]);
    float denom = 0.f;
#pragma unroll
    for (int j = 0; j < NO; ++j) {
        scores[j] = expf(scores[j] - mx);
        denom += scores[j];
    }
    const float inv = 1.f / denom;

    float o = 0.f;
#pragma unroll
    for (int j = 0; j < NO; ++j) {
        const int dlt = OFFSETS[j];
        if (t >= dlt) {
            o = fmaf(scores[j] * inv,
                     qkv[(size_t)(t - dlt) * QKV_N + 2 * DD + h * HDD + lane], o);
        }
    }
    outf[(size_t)t * DD + h * HDD + lane] = o;
}

extern "C" void kernel_launch(void* const* d_in, const int* in_sizes, int n_in,
                              void* d_out, int out_size, void* d_ws, size_t ws_size,
                              hipStream_t stream) {
    const float* x = (const float*)d_in[0];         // [4096,1024]
    const float* Wqkv = (const float*)d_in[1];      // [1024,3072]
    const float* bqkv = (const float*)d_in[2];      // [3072]
    const float* Wout = (const float*)d_in[3];      // [1024,1024]
    const float* bout = (const float*)d_in[4];      // [1024]
    const float* Wgate = (const float*)d_in[5];     // [1024,1024]
    const float* bgate = (const float*)d_in[6];     // [1024]
    const float* pos_bias = (const float*)d_in[7];  // [24,16]
    float* out = (float*)d_out;                     // [4096,1024]

    char* ws = (char*)d_ws;
    float* qkv = (float*)ws;                                  // 48 MB
    float* out_flat = (float*)(ws + (size_t)NN * QKV_N * 4);  // 16 MB
    float* gated = (float*)(ws + (size_t)NN * QKV_N * 4 + (size_t)NN * DD * 4);

    // 1) qkv = x @ Wqkv + bqkv
    {
        dim3 grid(QKV_N / 64, NN / 64);
        sgemm64<0><<<grid, 256, 0, stream>>>(x, Wqkv, bqkv, nullptr, qkv, NN, QKV_N, DD);
    }
    // 2) attention -> out_flat
    {
        const int waves = NN * HH;
        attn_kernel<<<waves / 4, 256, 0, stream>>>(qkv, pos_bias, out_flat);
    }
    // 3) gated = out_flat * sigmoid(x @ Wgate + bgate)
    {
        dim3 grid(DD / 64, NN / 64);
        sgemm64<1><<<grid, 256, 0, stream>>>(x, Wgate, bgate, out_flat, gated, NN, DD, DD);
    }
    // 4) out = gated @ Wout + bout
    {
        dim3 grid(DD / 64, NN / 64);
        sgemm64<0><<<grid, 256, 0, stream>>>(gated, Wout, bout, nullptr, out, NN, DD, DD);
    }
}

// Round 2
// 341.550 us; speedup vs baseline: 2.3552x; 2.3552x over previous
//
#include <hip/hip_runtime.h>
#include <hip/hip_bf16.h>

#define NN 4096
#define DD 1024
#define HH 16
#define HDD 64
#define NO 24
#define QKV_N (3 * DD)

typedef short bf16x8 __attribute__((ext_vector_type(8)));
typedef float f32x4 __attribute__((ext_vector_type(4)));
typedef unsigned short ushort;

__device__ __constant__ int OFFSETS[NO] = {0, 1, 2, 3, 4, 6, 8, 12, 16, 24, 32, 48,
                                           64, 96, 128, 192, 256, 384, 512, 768,
                                           1024, 1536, 2048, 3072};

// fp32 -> bf16 (RNE, inputs are finite/normal)
__device__ __forceinline__ ushort f2bf(float f) {
    unsigned u = __float_as_uint(f);
    return (ushort)((u + 0x7FFFu + ((u >> 16) & 1u)) >> 16);
}
__device__ __forceinline__ float bf2f(ushort u) {
    return __uint_as_float(((unsigned)u) << 16);
}

__device__ __forceinline__ void gload16(const void* g, void* l) {
    __builtin_amdgcn_global_load_lds((const __attribute__((address_space(1))) void*)g,
                                     (__attribute__((address_space(3))) void*)l, 16, 0, 0);
}

// ---------------------------------------------------------------------------
// elementwise fp32 -> bf16 (vectorized, 4/thread)
// ---------------------------------------------------------------------------
__global__ __launch_bounds__(256) void f2b_kernel(const float* __restrict__ in,
                                                  ushort* __restrict__ out, int n4) {
    int i = blockIdx.x * 256 + threadIdx.x;
    if (i < n4) {
        float4 v = ((const float4*)in)[i];
        ushort4 o;
        o.x = f2bf(v.x); o.y = f2bf(v.y); o.z = f2bf(v.z); o.w = f2bf(v.w);
        ((ushort4*)out)[i] = o;
    }
}

// ---------------------------------------------------------------------------
// transpose fp32 [R,C] -> bf16 [C,R]   (R,C multiples of 32)
// ---------------------------------------------------------------------------
__global__ __launch_bounds__(256) void transpose_f2b(const float* __restrict__ in,
                                                     ushort* __restrict__ out,
                                                     int R, int C) {
    __shared__ float tile[32][33];
    const int c0 = blockIdx.x * 32, r0 = blockIdx.y * 32;
    const int tx = threadIdx.x & 31, ty = threadIdx.x >> 5;  // ty: 0..7
#pragma unroll
    for (int i = 0; i < 32; i += 8)
        tile[ty + i][tx] = in[(size_t)(r0 + ty + i) * C + c0 + tx];
    __syncthreads();
#pragma unroll
    for (int i = 0; i < 32; i += 8)
        out[(size_t)(c0 + ty + i) * R + r0 + tx] = f2bf(tile[tx][ty + i]);
}

// ---------------------------------------------------------------------------
// bf16 MFMA GEMM: C[M,N] = A[M,K] @ BT[N,K]^T + bias
// 128x128 tile, BK=32, 256 threads (4 waves, each 64x64 = 4x4 frags of 16x16x32).
// LDS tiles [128 rows][32 k] bf16, XOR-swizzled (slot ^= (row>>1)&3) via
// pre-swizzled global source (linear global_load_lds dest) + swizzled ds_read.
// OP==0: fp32 out = acc + bias
// OP==1: bf16 out = acc + bias
// OP==2: bf16 out = mult[m,n] * sigmoid(acc + bias)
// ---------------------------------------------------------------------------
template <int OP>
__global__ __launch_bounds__(256) void mfma_gemm(const ushort* __restrict__ A,
                                                 const ushort* __restrict__ BT,
                                                 const float* __restrict__ bias,
                                                 const float* __restrict__ mult,
                                                 void* __restrict__ Cout,
                                                 int M, int N, int K) {
    __shared__ ushort sA[2][128 * 32];
    __shared__ ushort sB[2][128 * 32];

    const int tid = threadIdx.x;
    const int lane = tid & 63;
    const int w = tid >> 6;
    const int wr = w >> 1, wc = w & 1;
    const int m0 = blockIdx.y * 128, n0 = blockIdx.x * 128;

    // staging: chunk = inst*256 + tid; row = chunk>>2 (0..127); slot = chunk&3
    // global slot pre-swizzled so that swizzled ds_read finds linear data.
    const int row0 = tid >> 2, slot = tid & 3;
    const int row1 = row0 + 64;
    const int sw0 = slot ^ ((row0 >> 1) & 3);
    const int sw1 = slot ^ ((row1 >> 1) & 3);
    // LDS dest element offsets (wave-uniform base; HW adds lane*16B)
    const int dst0 = (tid & ~63) * 8;
    const int dst1 = (256 + (tid & ~63)) * 8;

    const size_t aOff0 = (size_t)(m0 + row0) * K + sw0 * 8;
    const size_t aOff1 = (size_t)(m0 + row1) * K + sw1 * 8;
    const size_t bOff0 = (size_t)(n0 + row0) * K + sw0 * 8;
    const size_t bOff1 = (size_t)(n0 + row1) * K + sw1 * 8;

    // fragment ds_read byte offsets within a [128][32] bf16 tile (64 B rows)
    const int ks = lane >> 4;  // k-slot 0..3
    int aRd[4], bRd[4];
#pragma unroll
    for (int m = 0; m < 4; ++m) {
        int r = wr * 64 + m * 16 + (lane & 15);
        aRd[m] = r * 64 + ((ks ^ ((r >> 1) & 3)) << 4);
    }
#pragma unroll
    for (int n = 0; n < 4; ++n) {
        int r = wc * 64 + n * 16 + (lane & 15);
        bRd[n] = r * 64 + ((ks ^ ((r >> 1) & 3)) << 4);
    }

    f32x4 acc[4][4];
#pragma unroll
    for (int m = 0; m < 4; ++m)
#pragma unroll
        for (int n = 0; n < 4; ++n) acc[m][n] = (f32x4){0.f, 0.f, 0.f, 0.f};

#define STAGE(buf, k0)                                              \
    do {                                                            \
        gload16(A + aOff0 + (k0), &sA[buf][dst0]);                  \
        gload16(A + aOff1 + (k0), &sA[buf][dst1]);                  \
        gload16(BT + bOff0 + (k0), &sB[buf][dst0]);                 \
        gload16(BT + bOff1 + (k0), &sB[buf][dst1]);                 \
    } while (0)

    const int NS = K >> 5;
    STAGE(0, 0);
    for (int s = 0; s < NS; ++s) {
        const int cur = s & 1;
        __syncthreads();  // drains vmcnt for buf[cur]; protects buf[cur^1] overwrite
        if (s + 1 < NS) STAGE(cur ^ 1, (s + 1) * 32);
        const char* pa = (const char*)sA[cur];
        const char* pb = (const char*)sB[cur];
        bf16x8 af[4], bfr[4];
#pragma unroll
        for (int m = 0; m < 4; ++m) af[m] = *(const bf16x8*)(pa + aRd[m]);
#pragma unroll
        for (int n = 0; n < 4; ++n) bfr[n] = *(const bf16x8*)(pb + bRd[n]);
#pragma unroll
        for (int m = 0; m < 4; ++m)
#pragma unroll
            for (int n = 0; n < 4; ++n)
                acc[m][n] = __builtin_amdgcn_mfma_f32_16x16x32_bf16(af[m], bfr[n],
                                                                    acc[m][n], 0, 0, 0);
    }
#undef STAGE

    // epilogue: C/D layout col = lane&15, row = (lane>>4)*4 + reg (m89-verified)
    const int fr = lane & 15, fq = lane >> 4;
#pragma unroll
    for (int m = 0; m < 4; ++m) {
#pragma unroll
        for (int n = 0; n < 4; ++n) {
            const int col = n0 + wc * 64 + n * 16 + fr;
            const float bv = bias[col];
#pragma unroll
            for (int j = 0; j < 4; ++j) {
                const int rrow = m0 + wr * 64 + m * 16 + fq * 4 + j;
                float v = acc[m][n][j] + bv;
                if (OP == 0) {
                    ((float*)Cout)[(size_t)rrow * N + col] = v;
                } else if (OP == 1) {
                    ((ushort*)Cout)[(size_t)rrow * N + col] = f2bf(v);
                } else {
                    const float g = mult[(size_t)rrow * N + col];
                    v = g / (1.f + expf(-v));
                    ((ushort*)Cout)[(size_t)rrow * N + col] = f2bf(v);
                }
            }
        }
    }
}

// ---------------------------------------------------------------------------
// Attention: one wave per (t, h). lane = head dim d (0..63). qkv is bf16.
// Invalid taps (t < delta) keep score = pos_bias (stay in softmax denom),
// contribute zero value.
// ---------------------------------------------------------------------------
__global__ __launch_bounds__(256) void attn_kernel(const ushort* __restrict__ qkv,
                                                   const float* __restrict__ pos_bias,
                                                   float* __restrict__ outf) {
    const int gwave = (blockIdx.x * 256 + threadIdx.x) >> 6;
    const int lane = threadIdx.x & 63;
    const int t = gwave >> 4;
    const int h = gwave & 15;
    const float scale = 0.125f;  // 64^-0.5

    const float q = bf2f(qkv[(size_t)t * QKV_N + h * HDD + lane]);

    float scores[NO];
#pragma unroll
    for (int j = 0; j < NO; ++j) {
        const int dlt = OFFSETS[j];
        float s = pos_bias[j * HH + h];
        if (t >= dlt) {  // wave-uniform branch
            float p = q * bf2f(qkv[(size_t)(t - dlt) * QKV_N + DD + h * HDD + lane]);
#pragma unroll
            for (int off = 32; off; off >>= 1) p += __shfl_xor(p, off);
            s = fmaf(p, scale, s);
        }
        scores[j] = s;
    }

    float mx = scores[0];
#pragma unroll
    for (int j = 1; j < NO; ++j) mx = fmaxf(mx, scores[j]);
    float denom = 0.f;
#pragma unroll
    for (int j = 0; j < NO; ++j) {
        scores[j] = expf(scores[j] - mx);
        denom += scores[j];
    }
    const float inv = 1.f / denom;

    float o = 0.f;
#pragma unroll
    for (int j = 0; j < NO; ++j) {
        const int dlt = OFFSETS[j];
        if (t >= dlt) {
            o = fmaf(scores[j] * inv,
                     bf2f(qkv[(size_t)(t - dlt) * QKV_N + 2 * DD + h * HDD + lane]), o);
        }
    }
    outf[(size_t)t * DD + h * HDD + lane] = o;
}

extern "C" void kernel_launch(void* const* d_in, const int* in_sizes, int n_in,
                              void* d_out, int out_size, void* d_ws, size_t ws_size,
                              hipStream_t stream) {
    const float* x = (const float*)d_in[0];         // [4096,1024]
    const float* Wqkv = (const float*)d_in[1];      // [1024,3072]
    const float* bqkv = (const float*)d_in[2];      // [3072]
    const float* Wout = (const float*)d_in[3];      // [1024,1024]
    const float* bout = (const float*)d_in[4];      // [1024]
    const float* Wgate = (const float*)d_in[5];     // [1024,1024]
    const float* bgate = (const float*)d_in[6];     // [1024]
    const float* pos_bias = (const float*)d_in[7];  // [24,16]
    float* out = (float*)d_out;                     // [4096,1024]

    // workspace layout (66 MB total)
    char* ws = (char*)d_ws;
    ushort* xb = (ushort*)ws;                        // 8 MB  [4096,1024] bf16
    ushort* WqkvT = (ushort*)(ws + (8u << 20));      // 6 MB  [3072,1024] bf16
    ushort* WgateT = (ushort*)(ws + (14u << 20));    // 2 MB  [1024,1024] bf16
    ushort* WoutT = (ushort*)(ws + (16u << 20));     // 2 MB  [1024,1024] bf16
    ushort* qkv = (ushort*)(ws + (18u << 20));       // 24 MB [4096,3072] bf16
    float* out_flat = (float*)(ws + (42u << 20));    // 16 MB [4096,1024] fp32
    ushort* gated = (ushort*)(ws + (58u << 20));     // 8 MB  [4096,1024] bf16

    // 0) converts / transposes
    f2b_kernel<<<(NN * DD / 4 + 255) / 256, 256, 0, stream>>>(x, xb, NN * DD / 4);
    transpose_f2b<<<dim3(QKV_N / 32, DD / 32), 256, 0, stream>>>(Wqkv, WqkvT, DD, QKV_N);
    transpose_f2b<<<dim3(DD / 32, DD / 32), 256, 0, stream>>>(Wgate, WgateT, DD, DD);
    transpose_f2b<<<dim3(DD / 32, DD / 32), 256, 0, stream>>>(Wout, WoutT, DD, DD);

    // 1) qkv = x @ Wqkv + bqkv  (bf16 out)
    mfma_gemm<1><<<dim3(QKV_N / 128, NN / 128), 256, 0, stream>>>(
        xb, WqkvT, bqkv, nullptr, qkv, NN, QKV_N, DD);
    // 2) attention -> out_flat (fp32)
    attn_kernel<<<NN * HH / 4, 256, 0, stream>>>(qkv, pos_bias, out_flat);
    // 3) gated = out_flat * sigmoid(x @ Wgate + bgate)  (bf16 out)
    mfma_gemm<2><<<dim3(DD / 128, NN / 128), 256, 0, stream>>>(
        xb, WgateT, bgate, out_flat, gated, NN, DD, DD);
    // 4) out = gated @ Wout + bout  (fp32 out)
    mfma_gemm<0><<<dim3(DD / 128, NN / 128), 256, 0, stream>>>(
        gated, WoutT, bout, nullptr, out, NN, DD, DD);
}

// Round 7
// 279.817 us; speedup vs baseline: 2.8748x; 1.2206x over previous
//
#include <hip/hip_runtime.h>
#include <hip/hip_bf16.h>

#define NN 4096
#define DD 1024
#define HH 16
#define HDD 64
#define NO 24
#define QKV_N (3 * DD)

typedef short bf16x8 __attribute__((ext_vector_type(8)));
typedef float f32x4 __attribute__((ext_vector_type(4)));
typedef unsigned short ushort;

// fp32 -> bf16 (RNE)
__device__ __forceinline__ ushort f2bf(float f) {
    unsigned u = __float_as_uint(f);
    return (ushort)((u + 0x7FFFu + ((u >> 16) & 1u)) >> 16);
}
__device__ __forceinline__ float bf2f(ushort u) {
    return __uint_as_float(((unsigned)u) << 16);
}

__device__ __forceinline__ void gload16(const void* g, void* l) {
    __builtin_amdgcn_global_load_lds((const __attribute__((address_space(1))) void*)g,
                                     (__attribute__((address_space(3))) void*)l, 16, 0, 0);
}

// ---------------------------------------------------------------------------
// elementwise fp32 -> bf16
// ---------------------------------------------------------------------------
__global__ __launch_bounds__(256) void f2b_kernel(const float* __restrict__ in,
                                                  ushort* __restrict__ out, int n4) {
    int i = blockIdx.x * 256 + threadIdx.x;
    if (i < n4) {
        float4 v = ((const float4*)in)[i];
        ushort4 o;
        o.x = f2bf(v.x); o.y = f2bf(v.y); o.z = f2bf(v.z); o.w = f2bf(v.w);
        ((ushort4*)out)[i] = o;
    }
}

// ---------------------------------------------------------------------------
// transpose fp32 [R,C] -> bf16 [C,R]
// ---------------------------------------------------------------------------
__global__ __launch_bounds__(256) void transpose_f2b(const float* __restrict__ in,
                                                     ushort* __restrict__ out,
                                                     int R, int C) {
    __shared__ float tile[32][33];
    const int c0 = blockIdx.x * 32, r0 = blockIdx.y * 32;
    const int tx = threadIdx.x & 31, ty = threadIdx.x >> 5;
#pragma unroll
    for (int i = 0; i < 32; i += 8)
        tile[ty + i][tx] = in[(size_t)(r0 + ty + i) * C + c0 + tx];
    __syncthreads();
#pragma unroll
    for (int i = 0; i < 32; i += 8)
        out[(size_t)(c0 + ty + i) * R + r0 + tx] = f2bf(tile[tx][ty + i]);
}

// ---------------------------------------------------------------------------
// bf16 MFMA GEMM: C = A[M,K] @ BT[N,K]^T + bias
// 128x128 tile, BK=32, 4 waves x (4x4) 16x16x32 frags, global_load_lds dbuf,
// XOR-swizzled LDS (slot ^= (row>>1)&3) via pre-swizzled global source.
// OP==0: fp32 out[m*N+n] = acc + bias
// OP==2: bf16 out = multT[n*M+m] * sigmoid(acc + bias)   (multT bf16 [N][M])
// OP==3: fp32 outT[n*M+m] = acc + bias  (transposed, float4 along m)
// ---------------------------------------------------------------------------
template <int OP>
__global__ __launch_bounds__(256) void mfma_gemm(const ushort* __restrict__ A,
                                                 const ushort* __restrict__ BT,
                                                 const float* __restrict__ bias,
                                                 const void* __restrict__ mult,
                                                 void* __restrict__ Cout,
                                                 int M, int N, int K) {
    __shared__ ushort sA[2][128 * 32];
    __shared__ ushort sB[2][128 * 32];

    const int tid = threadIdx.x;
    const int lane = tid & 63;
    const int w = tid >> 6;
    const int wr = w >> 1, wc = w & 1;
    const int m0 = blockIdx.y * 128, n0 = blockIdx.x * 128;

    const int row0 = tid >> 2, slot = tid & 3;
    const int row1 = row0 + 64;
    const int sw0 = slot ^ ((row0 >> 1) & 3);
    const int sw1 = slot ^ ((row1 >> 1) & 3);
    const int dst0 = (tid & ~63) * 8;
    const int dst1 = (256 + (tid & ~63)) * 8;

    const size_t aOff0 = (size_t)(m0 + row0) * K + sw0 * 8;
    const size_t aOff1 = (size_t)(m0 + row1) * K + sw1 * 8;
    const size_t bOff0 = (size_t)(n0 + row0) * K + sw0 * 8;
    const size_t bOff1 = (size_t)(n0 + row1) * K + sw1 * 8;

    const int ks = lane >> 4;
    int aRd[4], bRd[4];
#pragma unroll
    for (int m = 0; m < 4; ++m) {
        int r = wr * 64 + m * 16 + (lane & 15);
        aRd[m] = r * 64 + ((ks ^ ((r >> 1) & 3)) << 4);
    }
#pragma unroll
    for (int n = 0; n < 4; ++n) {
        int r = wc * 64 + n * 16 + (lane & 15);
        bRd[n] = r * 64 + ((ks ^ ((r >> 1) & 3)) << 4);
    }

    f32x4 acc[4][4];
#pragma unroll
    for (int m = 0; m < 4; ++m)
#pragma unroll
        for (int n = 0; n < 4; ++n) acc[m][n] = (f32x4){0.f, 0.f, 0.f, 0.f};

#define STAGE(buf, k0)                                              \
    do {                                                            \
        gload16(A + aOff0 + (k0), &sA[buf][dst0]);                  \
        gload16(A + aOff1 + (k0), &sA[buf][dst1]);                  \
        gload16(BT + bOff0 + (k0), &sB[buf][dst0]);                 \
        gload16(BT + bOff1 + (k0), &sB[buf][dst1]);                 \
    } while (0)

    const int NS = K >> 5;
    STAGE(0, 0);
    for (int s = 0; s < NS; ++s) {
        const int cur = s & 1;
        __syncthreads();
        if (s + 1 < NS) STAGE(cur ^ 1, (s + 1) * 32);
        const char* pa = (const char*)sA[cur];
        const char* pb = (const char*)sB[cur];
        bf16x8 af[4], bfr[4];
#pragma unroll
        for (int m = 0; m < 4; ++m) af[m] = *(const bf16x8*)(pa + aRd[m]);
#pragma unroll
        for (int n = 0; n < 4; ++n) bfr[n] = *(const bf16x8*)(pb + bRd[n]);
#pragma unroll
        for (int m = 0; m < 4; ++m)
#pragma unroll
            for (int n = 0; n < 4; ++n)
                acc[m][n] = __builtin_amdgcn_mfma_f32_16x16x32_bf16(af[m], bfr[n],
                                                                    acc[m][n], 0, 0, 0);
    }
#undef STAGE

    // C/D layout: col = lane&15, row = (lane>>4)*4 + j
    const int fr = lane & 15, fq = lane >> 4;
#pragma unroll
    for (int m = 0; m < 4; ++m) {
        const int rbase = m0 + wr * 64 + m * 16 + fq * 4;
#pragma unroll
        for (int n = 0; n < 4; ++n) {
            const int col = n0 + wc * 64 + n * 16 + fr;
            const float bv = bias[col];
            if (OP == 3) {
                float4 o4;
                o4.x = acc[m][n][0] + bv; o4.y = acc[m][n][1] + bv;
                o4.z = acc[m][n][2] + bv; o4.w = acc[m][n][3] + bv;
                *(float4*)&((float*)Cout)[(size_t)col * M + rbase] = o4;
            } else if (OP == 2) {
                const ushort4 mu =
                    *(const ushort4*)&((const ushort*)mult)[(size_t)col * M + rbase];
                const float mv[4] = {bf2f(mu.x), bf2f(mu.y), bf2f(mu.z), bf2f(mu.w)};
#pragma unroll
                for (int j = 0; j < 4; ++j) {
                    float v = acc[m][n][j] + bv;
                    v = mv[j] / (1.f + expf(-v));
                    ((ushort*)Cout)[(size_t)(rbase + j) * N + col] = f2bf(v);
                }
            } else {
#pragma unroll
                for (int j = 0; j < 4; ++j) {
                    ((float*)Cout)[(size_t)(rbase + j) * N + col] = acc[m][n][j] + bv;
                }
            }
        }
    }
}

// ---------------------------------------------------------------------------
// Attention, lane = t. One wave per (h, 64-t block).
// qkvT fp32 [3*1024 rows = (part,h,d)][4096 t]. Scores/probs lane-local in
// VGPRs; d-loop has only coalesced saddr+voffset loads and FMAs.
// Invalid taps: clamped load + final cndmask (score->pos_bias, p->0).
// Output transposed bf16 [h*64+d][t].
// ---------------------------------------------------------------------------
__global__ __launch_bounds__(256) void attn_kernel(const float* __restrict__ qkvT,
                                                   const float* __restrict__ pos_bias,
                                                   ushort* __restrict__ outT) {
    constexpr int OFF[NO] = {0, 1, 2, 3, 4, 6, 8, 12, 16, 24, 32, 48, 64, 96, 128,
                             192, 256, 384, 512, 768, 1024, 1536, 2048, 3072};
    // chunked XCD swizzle: 256 blocks -> 8 chunks of 32 (each XCD ~2 heads)
    const int bid = (blockIdx.x & 7) * 32 + (blockIdx.x >> 3);
    const int unit = bid * 4 + (threadIdx.x >> 6);
    const int lane = threadIdx.x & 63;
    const int h = unit >> 6;
    const int t = (unit & 63) * 64 + lane;

    const float* qd = qkvT + (size_t)(h * HDD) * NN;           // + d*NN
    const float* kd = qd + (size_t)DD * NN;
    const float* vd = qd + (size_t)(2 * DD) * NN;

    int kidx[NO];
#pragma unroll
    for (int j = 0; j < NO; ++j) kidx[j] = max(t - OFF[j], 0);

    float sc[NO];
#pragma unroll
    for (int j = 0; j < NO; ++j) sc[j] = 0.f;

#pragma unroll 2
    for (int d = 0; d < HDD; ++d) {
        const float qv = qd[(size_t)d * NN + t];
        const float* kr = kd + (size_t)d * NN;
#pragma unroll
        for (int j = 0; j < NO; ++j) sc[j] = fmaf(qv, kr[kidx[j]], sc[j]);
    }

    // score = valid ? dot*scale + pb : pb
#pragma unroll
    for (int j = 0; j < NO; ++j) {
        const float pb = pos_bias[j * HH + h];
        sc[j] = (t >= OFF[j]) ? fmaf(sc[j], 0.125f, pb) : pb;
    }

    float mx = sc[0];
#pragma unroll
    for (int j = 1; j < NO; ++j) mx = fmaxf(mx, sc[j]);
    float den = 0.f;
#pragma unroll
    for (int j = 0; j < NO; ++j) {
        sc[j] = __expf(sc[j] - mx);
        den += sc[j];
    }
    const float inv = 1.f / den;
#pragma unroll
    for (int j = 0; j < NO; ++j) sc[j] = (t >= OFF[j]) ? sc[j] * inv : 0.f;

#pragma unroll 2
    for (int d = 0; d < HDD; ++d) {
        const float* vr = vd + (size_t)d * NN;
        float o = 0.f;
#pragma unroll
        for (int j = 0; j < NO; ++j) o = fmaf(sc[j], vr[kidx[j]], o);
        outT[(size_t)(h * HDD + d) * NN + t] = f2bf(o);
    }
}

extern "C" void kernel_launch(void* const* d_in, const int* in_sizes, int n_in,
                              void* d_out, int out_size, void* d_ws, size_t ws_size,
                              hipStream_t stream) {
    const float* x = (const float*)d_in[0];
    const float* Wqkv = (const float*)d_in[1];
    const float* bqkv = (const float*)d_in[2];
    const float* Wout = (const float*)d_in[3];
    const float* bout = (const float*)d_in[4];
    const float* Wgate = (const float*)d_in[5];
    const float* bgate = (const float*)d_in[6];
    const float* pos_bias = (const float*)d_in[7];
    float* out = (float*)d_out;

    // workspace layout (74 MB peak; round-1 proved >= 80 MB exists)
    char* ws = (char*)d_ws;
    ushort* xb = (ushort*)ws;                            // 8 MB  [4096,1024] bf16
    ushort* WqkvT = (ushort*)(ws + ((size_t)8 << 20));   // 6 MB  [3072,1024] bf16
    ushort* WgateT = (ushort*)(ws + ((size_t)14 << 20)); // 2 MB
    ushort* WoutT = (ushort*)(ws + ((size_t)16 << 20));  // 2 MB
    float* qkvT = (float*)(ws + ((size_t)18 << 20));     // 48 MB [3072][4096] fp32
    ushort* outT = (ushort*)(ws + ((size_t)66 << 20));   // 8 MB  [1024][4096] bf16
    ushort* gated = (ushort*)(ws + ((size_t)18 << 20));  // overlays qkvT (dead)

    // 0) converts / transposes
    f2b_kernel<<<(NN * DD / 4 + 255) / 256, 256, 0, stream>>>(x, xb, NN * DD / 4);
    transpose_f2b<<<dim3(QKV_N / 32, DD / 32), 256, 0, stream>>>(Wqkv, WqkvT, DD, QKV_N);
    transpose_f2b<<<dim3(DD / 32, DD / 32), 256, 0, stream>>>(Wgate, WgateT, DD, DD);
    transpose_f2b<<<dim3(DD / 32, DD / 32), 256, 0, stream>>>(Wout, WoutT, DD, DD);

    // 1) qkvT = (x @ Wqkv + bqkv)^T  fp32 [3072][4096]
    mfma_gemm<3><<<dim3(QKV_N / 128, NN / 128), 256, 0, stream>>>(
        xb, WqkvT, bqkv, nullptr, qkvT, NN, QKV_N, DD);
    // 2) attention -> outT bf16 [1024][4096]
    attn_kernel<<<256, 256, 0, stream>>>(qkvT, pos_bias, outT);
    // 3) gated = outT^T * sigmoid(x @ Wgate + bgate)  bf16 [4096][1024]
    mfma_gemm<2><<<dim3(DD / 128, NN / 128), 256, 0, stream>>>(
        xb, WgateT, bgate, outT, gated, NN, DD, DD);
    // 4) out = gated @ Wout + bout  fp32
    mfma_gemm<0><<<dim3(DD / 128, NN / 128), 256, 0, stream>>>(
        gated, WoutT, bout, nullptr, out, NN, DD, DD);
}